// Round 11
// baseline (47.935 us; speedup 1.0000x reference)
//
#include <hip/hip_runtime.h>

#define NV 320
#define GV 640
#define DHALF 128
#define BSROWS 2048
#define K_DIM 512
#define LDA 40      // f16 per LDS row (32 + 8 pad)
#define NRED 40
#define NMT 128     // number of 16-row tiles

typedef _Float16 half8 __attribute__((ext_vector_type(8)));
typedef _Float16 half4 __attribute__((ext_vector_type(4)));
typedef float floatx4 __attribute__((ext_vector_type(4)));

#define MFMA16(a, b, c) __builtin_amdgcn_mfma_f32_16x16x32_f16(a, b, c, 0, 0, 0)

// ---------------- Prep: W[512][640] f32 -> Wth/Wtl [640][512] f16 (scale 1024); zero ctr ---
__global__ __launch_bounds__(256) void prep_w_kernel(
    const float* __restrict__ W, _Float16* __restrict__ Wth, _Float16* __restrict__ Wtl,
    int* __restrict__ counter) {
  __shared__ float T[32][33];
  const int k0 = blockIdx.y * 32, n0 = blockIdx.x * 32;
  const int t = threadIdx.x;
  if (blockIdx.x == 0 && blockIdx.y == 0 && t == 0) *counter = 0;
  const int r = t >> 3, c4 = (t & 7) << 2;
  float4 v = *(const float4*)(W + (k0 + r) * GV + n0 + c4);
  T[r][c4 + 0] = v.x; T[r][c4 + 1] = v.y; T[r][c4 + 2] = v.z; T[r][c4 + 3] = v.w;
  __syncthreads();
  const int nr = t >> 3, k4 = (t & 7) << 2;
  half4 hv, lv;
#pragma unroll
  for (int j = 0; j < 4; ++j) {
    float s = T[k4 + j][nr] * 1024.0f;
    _Float16 h = (_Float16)s;
    hv[j] = h;
    lv[j] = (_Float16)(s - (float)h);
  }
  *(half4*)(Wth + (n0 + nr) * K_DIM + k0 + k4) = hv;
  *(half4*)(Wtl + (n0 + nr) * K_DIM + k0 + k4) = lv;
}

// ---------------- Fused GEMM + row phase: 256 blocks, 16 rows x one group each -------------
__global__ __launch_bounds__(256) void gemm_row_kernel(
    const float* __restrict__ X, const _Float16* __restrict__ Wth,
    const _Float16* __restrict__ Wtl, const float* __restrict__ bias,
    const float* __restrict__ gum, const float* __restrict__ cvs,
    float* __restrict__ out, float* __restrict__ part) {
  __shared__ _Float16 Ah[2][16 * LDA], Al[2][16 * LDA];
  __shared__ float sm_m[4][16], sm_av[4][16], sm_s[4][16];
  __shared__ int sm_ai[4][16], sm_idx[16];

  const int tid = threadIdx.x;
  const int bid = blockIdx.x;
  const int g = bid & 1;
  const int mtile = bid >> 1;       // 0..127
  const int bm = mtile * 16;
  const int w = tid >> 6, lane = tid & 63;
  const int wcol0 = w * 80;
  const int gn0 = g * NV;

  // A staging: srow = tid>>4 (0..15), skc = (tid&15)*2 (float2 per thread)
  const int srow = tid >> 4, skc = (tid & 15) << 1;
  const float* Xg = X + (bm + srow) * K_DIM + skc;
  const int sA = srow * LDA + skc;

  const int frow = lane & 15;        // A row-in-tile / B col-in-16
  const int rq0 = (lane >> 4) << 2;  // C/D row base
  const int fkg = (lane >> 4) << 3;  // k offset of fragment

  // B fragment base: col = gn0 + wcol0 + j*16 + frow, layout [n][k]
  const _Float16* Bhp = Wth + (gn0 + wcol0 + frow) * K_DIM;
  const _Float16* Blp = Wtl + (gn0 + wcol0 + frow) * K_DIM;

  floatx4 acc[5] = {};

  auto stageA = [&](int buf, float2 xv) {
#pragma unroll
    for (int j = 0; j < 2; ++j) {
      float s = ((j == 0) ? xv.x : xv.y) * 64.0f;
      _Float16 h = (_Float16)s;
      Ah[buf][sA + j] = h;
      Al[buf][sA + j] = (_Float16)(s - (float)h);
    }
  };

  stageA(0, *(const float2*)(Xg));
  __syncthreads();

  for (int k0 = 0; k0 < K_DIM; k0 += 32) {
    const int cur = (k0 >> 5) & 1;
    const bool more = (k0 + 32) < K_DIM;

    float2 xv;
    if (more) xv = *(const float2*)(Xg + k0 + 32);

    half8 ah = *(const half8*)&Ah[cur][frow * LDA + fkg];
    half8 al = *(const half8*)&Al[cur][frow * LDA + fkg];

#pragma unroll
    for (int j = 0; j < 5; ++j) {
      half8 bh = *(const half8*)(Bhp + j * 16 * K_DIM + k0 + fkg);
      half8 bl = *(const half8*)(Blp + j * 16 * K_DIM + k0 + fkg);
      // per-output order hh, hl, lh (bit-identical to validated rounds)
      acc[j] = MFMA16(ah, bh, acc[j]);
      acc[j] = MFMA16(ah, bl, acc[j]);
      acc[j] = MFMA16(al, bh, acc[j]);
    }

    if (more) stageA(cur ^ 1, xv);
    __syncthreads();
  }

  // ---------------- epilogue ----------------
  const float inv = 1.0f / 65536.0f;
#pragma unroll
  for (int j = 0; j < 5; ++j) {
    const float bb = bias[gn0 + wcol0 + j * 16 + frow];
#pragma unroll
    for (int q = 0; q < 4; ++q) acc[j][q] = acc[j][q] * inv + bb;
  }

  // gumbels: lane's 4 rows x 5 cols
  float gv[5][4];
#pragma unroll
  for (int q = 0; q < 4; ++q) {
    const int r = bm + rq0 + q;
    const float* gr = gum + (2 * r + g) * NV + wcol0 + frow;
#pragma unroll
    for (int j = 0; j < 5; ++j) gv[j][q] = gr[j * 16];
  }

  // per-row max (raw logits) + argmax (l+gumbel, tie -> lowest col), 16-lane tree
  float m[4], bv[4];
  int bi[4];
#pragma unroll
  for (int q = 0; q < 4; ++q) {
    float mm = acc[0][q];
    float av = acc[0][q] + gv[0][q];
    int ai = wcol0 + frow;
#pragma unroll
    for (int j = 1; j < 5; ++j) {
      mm = fmaxf(mm, acc[j][q]);
      float a2 = acc[j][q] + gv[j][q];
      if (a2 > av) { av = a2; ai = wcol0 + j * 16 + frow; }
    }
#pragma unroll
    for (int o = 1; o < 16; o <<= 1) {
      mm = fmaxf(mm, __shfl_xor(mm, o));
      float ov = __shfl_xor(av, o);
      int oi = __shfl_xor(ai, o);
      if (ov > av || (ov == av && oi < ai)) { av = ov; ai = oi; }
    }
    m[q] = mm; bv[q] = av; bi[q] = ai;
  }
  if (frow == 0) {
#pragma unroll
    for (int q = 0; q < 4; ++q) {
      sm_m[w][rq0 + q] = m[q];
      sm_av[w][rq0 + q] = bv[q];
      sm_ai[w][rq0 + q] = bi[q];
    }
  }
  __syncthreads();

  float gm[4];
#pragma unroll
  for (int q = 0; q < 4; ++q) {
    const int row = rq0 + q;
    float mm = sm_m[0][row];
    float av = sm_av[0][row];
    int ai = sm_ai[0][row];
#pragma unroll
    for (int ww = 1; ww < 4; ++ww) {
      mm = fmaxf(mm, sm_m[ww][row]);
      float v2 = sm_av[ww][row];
      int i2 = sm_ai[ww][row];
      if (v2 > av || (v2 == av && i2 < ai)) { av = v2; ai = i2; }
    }
    gm[q] = mm;
    if (w == 0 && frow == 0) sm_idx[row] = ai;
  }

  // exp + per-row sum
  float rs[4];
#pragma unroll
  for (int q = 0; q < 4; ++q) {
    float s = 0.f;
#pragma unroll
    for (int j = 0; j < 5; ++j) {
      float e = expf(acc[j][q] - gm[q]);
      acc[j][q] = e;
      s += e;
    }
#pragma unroll
    for (int o = 1; o < 16; o <<= 1) s += __shfl_xor(s, o);
    rs[q] = s;
  }
  if (frow == 0)
#pragma unroll
    for (int q = 0; q < 4; ++q) sm_s[w][rq0 + q] = rs[q];
  __syncthreads();

  float rinv[4];
#pragma unroll
  for (int q = 0; q < 4; ++q) {
    const int row = rq0 + q;
    rinv[q] = 1.f / ((sm_s[0][row] + sm_s[1][row]) + (sm_s[2][row] + sm_s[3][row]));
  }

  // marginal partials: col-sum over this block's 16 rows
#pragma unroll
  for (int j = 0; j < 5; ++j) {
    float p = 0.f;
#pragma unroll
    for (int q = 0; q < 4; ++q) p += acc[j][q] * rinv[q];
    p += __shfl_xor(p, 16);
    p += __shfl_xor(p, 32);
    if (lane < 16) part[(g * NMT + mtile) * NV + wcol0 + j * 16 + lane] = p;
  }

  // fused gather: 16 rows x 128 floats = 512 float4, 2 iters of 256 threads
#pragma unroll
  for (int it = 0; it < 2; ++it) {
    const int f4 = tid + it * 256;
    const int row = f4 >> 5;
    const int d = (f4 & 31) << 2;
    const int id = sm_idx[row];
    const float4 v = *(const float4*)(cvs + (g * NV + id) * DHALF + d);
    *(float4*)(out + (bm + row) * 256 + g * DHALF + d) = v;
  }
}

// ---------------- Reduce partials + perplexity: 40 blocks x 16 cols, 128 partials/group ----
__global__ __launch_bounds__(256) void reduce_perp_kernel(
    const float* __restrict__ part, float* __restrict__ hpart,
    int* __restrict__ counter, float* __restrict__ perpOut) {
  const int t = threadIdx.x;
  const int rg = t >> 4, co = t & 15;
  const int col = blockIdx.x * 16 + co;  // 0..639; blocks 0..19 group0, 20..39 group1
  const int g = (col >= NV) ? 1 : 0;
  const int c = col - g * NV;
  float s = 0.f;
  for (int b = rg; b < NMT; b += 16) s += part[(g * NMT + b) * NV + c];
  __shared__ float red[16][16];
  red[rg][co] = s;
  __syncthreads();
  if (t < 16) {
    float cs = 0.f;
#pragma unroll
    for (int j = 0; j < 16; ++j) cs += red[j][t];
    const float mm = cs * (1.0f / BSROWS);
    float h = mm * logf(mm + 1e-7f);
#pragma unroll
    for (int o = 8; o > 0; o >>= 1) h += __shfl_xor(h, o, 16);
    if (t == 0) {
      hpart[blockIdx.x] = h;
      __threadfence();
      const int old = atomicAdd(counter, 1);
      if (old == NRED - 1) {
        __threadfence();
        float h0 = 0.f, h1 = 0.f;
#pragma unroll
        for (int i = 0; i < 20; ++i) h0 += hpart[i];
#pragma unroll
        for (int i = 20; i < 40; ++i) h1 += hpart[i];
        perpOut[0] = expf(-h0) + expf(-h1);
      }
    }
  }
}

extern "C" void kernel_launch(void* const* d_in, const int* in_sizes, int n_in,
                              void* d_out, int out_size, void* d_ws, size_t ws_size,
                              hipStream_t stream) {
  const float* x = (const float*)d_in[0];
  const float* W = (const float*)d_in[1];
  const float* b = (const float*)d_in[2];
  const float* cvs = (const float*)d_in[3];
  const float* gum = (const float*)d_in[4];
  float* out = (float*)d_out;

  float* part = (float*)d_ws;                 // 256*320 f32
  float* hpart = part + 2 * NMT * NV;         // 40 f32 (+pad)
  int* counter = (int*)(hpart + 64);          // 1 i32
  _Float16* Wth = (_Float16*)(counter + 4);   // 640*512 f16
  _Float16* Wtl = Wth + GV * K_DIM;           // 640*512 f16

  dim3 pgrid(GV / 32, K_DIM / 32);  // (20, 16)
  prep_w_kernel<<<pgrid, 256, 0, stream>>>(W, Wth, Wtl, counter);
  gemm_row_kernel<<<256, 256, 0, stream>>>(x, Wth, Wtl, b, gum, cvs, out, part);
  reduce_perp_kernel<<<NRED, 256, 0, stream>>>(part, hpart, counter, out + BSROWS * 256);
}

// Round 12
// 31.437 us; speedup vs baseline: 1.5248x; 1.5248x over previous
//
#include <hip/hip_runtime.h>

#define NV 320
#define GV 640
#define DHALF 128
#define BSROWS 2048
#define K_DIM 512
#define LDA 40      // f16 per LDS row (32 + 8 pad)
#define NRED 40
#define NMT 128     // number of 16-row tiles per group

typedef _Float16 half8 __attribute__((ext_vector_type(8)));
typedef float floatx4 __attribute__((ext_vector_type(4)));

#define MFMA16(a, b, c) __builtin_amdgcn_mfma_f32_16x16x32_f16(a, b, c, 0, 0, 0)

// ---------------- Fused GEMM + row phase: 256 blocks, 16 rows x one group each -------------
// A: X*64 -> f16 hi/lo via double-buffered LDS (validated). B: W*1024 hi/lo split in-reg
// from prefetched f32 (validated values/order). Epilogue: softmax/argmax/gather/partials.
__global__ __launch_bounds__(256) void gemm_row_kernel(
    const float* __restrict__ X, const float* __restrict__ W,
    const float* __restrict__ bias, const float* __restrict__ gum,
    const float* __restrict__ cvs, float* __restrict__ out,
    float* __restrict__ part, int* __restrict__ counter) {
  __shared__ _Float16 Ah[2][16 * LDA], Al[2][16 * LDA];
  __shared__ float sm_m[4][16], sm_av[4][16], sm_s[4][16];
  __shared__ int sm_ai[4][16], sm_idx[16];

  const int tid = threadIdx.x;
  const int bid = blockIdx.x;
  if (bid == 0 && tid == 0) *counter = 0;
  const int g = bid & 1;
  const int mtile = bid >> 1;  // 0..127
  const int bm = mtile * 16;
  const int w = tid >> 6, lane = tid & 63;
  const int wcol0 = w * 80;
  const int gn0 = g * NV;

  // A staging: srow = tid>>4 (0..15), skc = (tid&15)*2 (float2 per thread)
  const int srow = tid >> 4, skc = (tid & 15) << 1;
  const float* Xg = X + (bm + srow) * K_DIM + skc;
  const int sA = srow * LDA + skc;

  const int frow = lane & 15;        // A row-in-tile / B col-in-16
  const int rq0 = (lane >> 4) << 2;  // C/D row base
  const int fkg = (lane >> 4) << 3;  // k offset of fragment
  const float* Wf = W + gn0 + wcol0 + frow;

  // ---- gumbel prefetch (hidden under the GEMM) ----
  float gv[5][4];
#pragma unroll
  for (int q = 0; q < 4; ++q) {
    const int r = bm + rq0 + q;
    const float* gr = gum + (2 * r + g) * NV + wcol0 + frow;
#pragma unroll
    for (int j = 0; j < 5; ++j) gv[j][q] = gr[j * 16];
  }

  floatx4 acc[5] = {};

  auto stageA = [&](int buf, float2 xv) {
#pragma unroll
    for (int j = 0; j < 2; ++j) {
      float s = ((j == 0) ? xv.x : xv.y) * 64.0f;
      _Float16 h = (_Float16)s;
      Ah[buf][sA + j] = h;
      Al[buf][sA + j] = (_Float16)(s - (float)h);
    }
  };
  auto loadW = [&](int k0, float (&wv)[5][8]) {
#pragma unroll
    for (int j = 0; j < 5; ++j)
#pragma unroll
      for (int kk = 0; kk < 8; ++kk)
        wv[j][kk] = Wf[(k0 + fkg + kk) * GV + j * 16];
  };
  auto computeTile = [&](int buf, const float (&wv)[5][8]) {
    half8 ah = *(const half8*)&Ah[buf][frow * LDA + fkg];
    half8 al = *(const half8*)&Al[buf][frow * LDA + fkg];
#pragma unroll
    for (int j = 0; j < 5; ++j) {
      half8 bh, bl;
#pragma unroll
      for (int kk = 0; kk < 8; ++kk) {
        float s = wv[j][kk] * 1024.0f;
        _Float16 h = (_Float16)s;
        bh[kk] = h;
        bl[kk] = (_Float16)(s - (float)h);
      }
      // per-output order hh, hl, lh (bit-identical to validated rounds)
      acc[j] = MFMA16(ah, bh, acc[j]);
      acc[j] = MFMA16(ah, bl, acc[j]);
      acc[j] = MFMA16(al, bh, acc[j]);
    }
  };

  float wvA[5][8], wvB[5][8];
  stageA(0, *(const float2*)(Xg));
  loadW(0, wvA);
  __syncthreads();

  // 8 iterations, 2 k-tiles each; A double-buffer 0/1; W reg double-buffer A/B
  for (int k0 = 0; k0 < K_DIM; k0 += 64) {
    const bool more = (k0 + 64) < K_DIM;

    float2 xv1 = *(const float2*)(Xg + k0 + 32);
    loadW(k0 + 32, wvB);            // prefetch odd tile
    computeTile(0, wvA);            // compute even tile
    stageA(1, xv1);
    __syncthreads();

    float2 xv2;
    if (more) {
      xv2 = *(const float2*)(Xg + k0 + 64);
      loadW(k0 + 64, wvA);          // prefetch next even tile
    }
    computeTile(1, wvB);            // compute odd tile
    if (more) stageA(0, xv2);
    __syncthreads();
  }

  // ---------------- epilogue ----------------
  const float inv = 1.0f / 65536.0f;
#pragma unroll
  for (int j = 0; j < 5; ++j) {
    const float bb = bias[gn0 + wcol0 + j * 16 + frow];
#pragma unroll
    for (int q = 0; q < 4; ++q) acc[j][q] = acc[j][q] * inv + bb;
  }

  // per-row max (raw logits) + argmax (l+gumbel, tie -> lowest col), 16-lane tree
  float m[4], bv[4];
  int bi[4];
#pragma unroll
  for (int q = 0; q < 4; ++q) {
    float mm = acc[0][q];
    float av = acc[0][q] + gv[0][q];
    int ai = wcol0 + frow;
#pragma unroll
    for (int j = 1; j < 5; ++j) {
      mm = fmaxf(mm, acc[j][q]);
      float a2 = acc[j][q] + gv[j][q];
      if (a2 > av) { av = a2; ai = wcol0 + j * 16 + frow; }
    }
#pragma unroll
    for (int o = 1; o < 16; o <<= 1) {
      mm = fmaxf(mm, __shfl_xor(mm, o));
      float ov = __shfl_xor(av, o);
      int oi = __shfl_xor(ai, o);
      if (ov > av || (ov == av && oi < ai)) { av = ov; ai = oi; }
    }
    m[q] = mm; bv[q] = av; bi[q] = ai;
  }
  if (frow == 0) {
#pragma unroll
    for (int q = 0; q < 4; ++q) {
      sm_m[w][rq0 + q] = m[q];
      sm_av[w][rq0 + q] = bv[q];
      sm_ai[w][rq0 + q] = bi[q];
    }
  }
  __syncthreads();

  float gm[4];
#pragma unroll
  for (int q = 0; q < 4; ++q) {
    const int row = rq0 + q;
    float mm = sm_m[0][row];
    float av = sm_av[0][row];
    int ai = sm_ai[0][row];
#pragma unroll
    for (int ww = 1; ww < 4; ++ww) {
      mm = fmaxf(mm, sm_m[ww][row]);
      float v2 = sm_av[ww][row];
      int i2 = sm_ai[ww][row];
      if (v2 > av || (v2 == av && i2 < ai)) { av = v2; ai = i2; }
    }
    gm[q] = mm;
    if (w == 0 && frow == 0) sm_idx[row] = ai;
  }

  // exp + per-row sum
  float rs[4];
#pragma unroll
  for (int q = 0; q < 4; ++q) {
    float s = 0.f;
#pragma unroll
    for (int j = 0; j < 5; ++j) {
      float e = expf(acc[j][q] - gm[q]);
      acc[j][q] = e;
      s += e;
    }
#pragma unroll
    for (int o = 1; o < 16; o <<= 1) s += __shfl_xor(s, o);
    rs[q] = s;
  }
  if (frow == 0)
#pragma unroll
    for (int q = 0; q < 4; ++q) sm_s[w][rq0 + q] = rs[q];
  __syncthreads();

  float rinv[4];
#pragma unroll
  for (int q = 0; q < 4; ++q) {
    const int row = rq0 + q;
    rinv[q] = 1.f / ((sm_s[0][row] + sm_s[1][row]) + (sm_s[2][row] + sm_s[3][row]));
  }

  // marginal partials: col-sum over this block's 16 rows
#pragma unroll
  for (int j = 0; j < 5; ++j) {
    float p = 0.f;
#pragma unroll
    for (int q = 0; q < 4; ++q) p += acc[j][q] * rinv[q];
    p += __shfl_xor(p, 16);
    p += __shfl_xor(p, 32);
    if (lane < 16) part[(g * NMT + mtile) * NV + wcol0 + j * 16 + lane] = p;
  }

  // fused gather: 16 rows x 128 floats = 512 float4, 2 iters of 256 threads
#pragma unroll
  for (int it = 0; it < 2; ++it) {
    const int f4 = tid + it * 256;
    const int row = f4 >> 5;
    const int d = (f4 & 31) << 2;
    const int id = sm_idx[row];
    const float4 v = *(const float4*)(cvs + (g * NV + id) * DHALF + d);
    *(float4*)(out + (bm + row) * 256 + g * DHALF + d) = v;
  }
}

// ---------------- Reduce partials + perplexity: 40 blocks x 16 cols, 128 partials/group ----
__global__ __launch_bounds__(256) void reduce_perp_kernel(
    const float* __restrict__ part, float* __restrict__ hpart,
    int* __restrict__ counter, float* __restrict__ perpOut) {
  const int t = threadIdx.x;
  const int rg = t >> 4, co = t & 15;
  const int col = blockIdx.x * 16 + co;  // 0..639; blocks 0..19 group0, 20..39 group1
  const int g = (col >= NV) ? 1 : 0;
  const int c = col - g * NV;
  float s = 0.f;
  for (int b = rg; b < NMT; b += 16) s += part[(g * NMT + b) * NV + c];
  __shared__ float red[16][16];
  red[rg][co] = s;
  __syncthreads();
  if (t < 16) {
    float cs = 0.f;
#pragma unroll
    for (int j = 0; j < 16; ++j) cs += red[j][t];
    const float mm = cs * (1.0f / BSROWS);
    float h = mm * logf(mm + 1e-7f);
#pragma unroll
    for (int o = 8; o > 0; o >>= 1) h += __shfl_xor(h, o, 16);
    if (t == 0) {
      hpart[blockIdx.x] = h;
      __threadfence();
      const int old = atomicAdd(counter, 1);
      if (old == NRED - 1) {
        __threadfence();
        float h0 = 0.f, h1 = 0.f;
#pragma unroll
        for (int i = 0; i < 20; ++i) h0 += hpart[i];
#pragma unroll
        for (int i = 20; i < 40; ++i) h1 += hpart[i];
        perpOut[0] = expf(-h0) + expf(-h1);
      }
    }
  }
}

extern "C" void kernel_launch(void* const* d_in, const int* in_sizes, int n_in,
                              void* d_out, int out_size, void* d_ws, size_t ws_size,
                              hipStream_t stream) {
  const float* x = (const float*)d_in[0];
  const float* W = (const float*)d_in[1];
  const float* b = (const float*)d_in[2];
  const float* cvs = (const float*)d_in[3];
  const float* gum = (const float*)d_in[4];
  float* out = (float*)d_out;

  float* part = (float*)d_ws;                 // 256*320 f32
  float* hpart = part + 2 * NMT * NV;         // 40 f32 (+pad)
  int* counter = (int*)(hpart + 64);          // 1 i32

  gemm_row_kernel<<<256, 256, 0, stream>>>(x, W, b, gum, cvs, out, part, counter);
  reduce_perp_kernel<<<NRED, 256, 0, stream>>>(part, hpart, counter, out + BSROWS * 256);
}